// Round 2
// baseline (496.279 us; speedup 1.0000x reference)
//
#include <hip/hip_runtime.h>
#include <math.h>

// Problem constants (from reference):
#define NROWS 1000000
#define NF    64      // N_FIXED
#define BB    5000    // B
#define LLg   10      // L
#define TTg   25      // T
#define KKg   8       // K

// ws layout (in floats):
//   [0,   80)   rho   = tanh(raw_rho)          (L,K)
//   [80, 160)   d     = diag(chol(Sigma[k]))   (L,K)
//   [160, 672)  betaT[k][f] = beta[f][k]       (K,NF)
//   [1024, 1024+T*B*L*K)  u table (T,B,L,K)    40 MB
#define WS_RHO   0
#define WS_D     80
#define WS_BETAT 160
#define WS_U     1024

// ---------------------------------------------------------------------------
// Prep: rho = tanh(raw_rho); d = diag of per-k Cholesky(Sigma); betaT.
// ---------------------------------------------------------------------------
__global__ void prep_kernel(const float* __restrict__ beta,
                            const float* __restrict__ raw_rho,
                            const float* __restrict__ Sigma,
                            float* __restrict__ ws) {
    const int tid = threadIdx.x;
    for (int i = tid; i < LLg * KKg; i += blockDim.x)
        ws[WS_RHO + i] = tanhf(raw_rho[i]);
    for (int i = tid; i < KKg * NF; i += blockDim.x) {
        const int k = i / NF, f = i % NF;
        ws[WS_BETAT + i] = beta[f * KKg + k];
    }
    if (tid < KKg) {
        const int k = tid;
        float Lf[LLg][LLg];
        const float* S = Sigma + k * LLg * LLg;
        for (int i = 0; i < LLg; ++i) {
            for (int j = 0; j <= i; ++j) {
                float s = S[i * LLg + j];
                for (int m = 0; m < j; ++m) s -= Lf[i][m] * Lf[j][m];
                if (i == j) Lf[i][i] = sqrtf(s);
                else        Lf[i][j] = s / Lf[j][j];
            }
        }
        for (int l = 0; l < LLg; ++l)
            ws[WS_D + l * KKg + k] = Lf[l][l];
    }
}

// ---------------------------------------------------------------------------
// u table: u[t,b,l,k] AR(1) recurrence. One thread per (b,l,k) = 400k threads.
// ---------------------------------------------------------------------------
__global__ __launch_bounds__(256) void u_kernel(const float* __restrict__ eps,
                                                const float* __restrict__ ws,
                                                float* __restrict__ u) {
    const int tid = blockIdx.x * blockDim.x + threadIdx.x;
    if (tid >= BB * LLg * KKg) return;
    const int k = tid % KKg;
    const int l = (tid / KKg) % LLg;
    const int b = tid / (KKg * LLg);
    const float rho = ws[WS_RHO + l * KKg + k];
    const float dv  = ws[WS_D   + l * KKg + k];
    const float* ep = eps + ((size_t)(b * LLg + l) * TTg) * KKg + k;
    float* up = u + (size_t)(b * LLg + l) * KKg + k;   // t=0 slot
    const size_t ustride = (size_t)BB * LLg * KKg;     // stride in t
    float uv = ep[0];
    up[0] = uv;
    for (int t = 1; t < TTg; ++t) {
        uv = rho * uv + dv * ep[(size_t)t * KKg];
        up[(size_t)t * ustride] = uv;
    }
}

// ---------------------------------------------------------------------------
// Main: out[row,k] = dot(X[row,:], beta[:,k]) + u[sea,bat,lea,k]
// FLAT structure (no grid-stride loop): each 8-lane group handles exactly
// TWO adjacent rows; lane c of a group owns k=c. 4M threads / 15625 blocks
// cover all 1M rows exactly. Rationale: the R1 version looped 8 rows/thread
// with a serial ids->u dependent chain per iteration and was latency-bound
// at 17% HBM. Here every thread has ONE short chain; MLP comes from 244
// queued waves/CU instead of serial iterations.
// ---------------------------------------------------------------------------
template <bool USE_TABLE>
__global__ __launch_bounds__(256) void main_kernel(
    const float* __restrict__ X,
    const int*   __restrict__ bat,
    const int*   __restrict__ lea,
    const int*   __restrict__ sea,
    const float* __restrict__ ws,
    const float* __restrict__ u_table,
    const float* __restrict__ eps,
    float*       __restrict__ out)
{
    const int gt  = blockIdx.x * blockDim.x + threadIdx.x;
    const int c   = gt & 7;          // which k this lane owns
    const int g   = gt >> 3;         // group id, 0..499999
    const int row0 = g * 2;          // exact cover, no guard needed

    // --- chain head: ids for both rows (6 independent loads) ---
    const int b0 = bat[row0],     b1 = bat[row0 + 1];
    const int l0 = lea[row0],     l1 = lea[row0 + 1];
    const int t0 = sea[row0],     t1 = sea[row0 + 1];

    // --- u values (2 independent gathers, dependent only on ids) ---
    float uv0, uv1;
    if (USE_TABLE) {
        uv0 = u_table[(((size_t)t0 * BB + b0) * LLg + l0) * KKg + c];
        uv1 = u_table[(((size_t)t1 * BB + b1) * LLg + l1) * KKg + c];
    } else {
        const float rho0 = ws[WS_RHO + l0 * KKg + c];
        const float dv0  = ws[WS_D   + l0 * KKg + c];
        const float* e0  = eps + ((size_t)(b0 * LLg + l0) * TTg) * KKg + c;
        uv0 = e0[0];
        for (int tt = 1; tt <= t0; ++tt) uv0 = rho0 * uv0 + dv0 * e0[(size_t)tt * KKg];
        const float rho1 = ws[WS_RHO + l1 * KKg + c];
        const float dv1  = ws[WS_D   + l1 * KKg + c];
        const float* e1  = eps + ((size_t)(b1 * LLg + l1) * TTg) * KKg + c;
        uv1 = e1[0];
        for (int tt = 1; tt <= t1; ++tt) uv1 = rho1 * uv1 + dv1 * e1[(size_t)tt * KKg];
    }

    // --- beta column c -> registers (16 coalesced float4, L1-broadcast) ---
    float bc[NF];
    const float4* bt4 = (const float4*)(ws + WS_BETAT + c * NF);
#pragma unroll
    for (int j = 0; j < NF / 4; ++j) {
        const float4 v = bt4[j];
        bc[4 * j + 0] = v.x; bc[4 * j + 1] = v.y;
        bc[4 * j + 2] = v.z; bc[4 * j + 3] = v.w;
    }

    // --- X rows (contiguous 512 B per group; 8-way same-address broadcast
    //     within group merges in the coalescer) ---
    const float4* x4 = (const float4*)(X + (size_t)row0 * NF);
    float acc0 = 0.f, acc1 = 0.f;
#pragma unroll
    for (int j = 0; j < NF / 4; ++j) {
        const float4 v = x4[j];
        acc0 += v.x * bc[4 * j + 0] + v.y * bc[4 * j + 1]
              + v.z * bc[4 * j + 2] + v.w * bc[4 * j + 3];
    }
#pragma unroll
    for (int j = 0; j < NF / 4; ++j) {
        const float4 v = x4[NF / 4 + j];
        acc1 += v.x * bc[4 * j + 0] + v.y * bc[4 * j + 1]
              + v.z * bc[4 * j + 2] + v.w * bc[4 * j + 3];
    }

    out[(size_t)row0 * KKg + c]       = acc0 + uv0;
    out[(size_t)(row0 + 1) * KKg + c] = acc1 + uv1;
}

extern "C" void kernel_launch(void* const* d_in, const int* in_sizes, int n_in,
                              void* d_out, int out_size, void* d_ws, size_t ws_size,
                              hipStream_t stream) {
    const float* X       = (const float*)d_in[0];
    const int*   bat     = (const int*)  d_in[1];
    const int*   lea     = (const int*)  d_in[2];
    const int*   sea     = (const int*)  d_in[3];
    const float* beta    = (const float*)d_in[4];
    const float* raw_rho = (const float*)d_in[5];
    const float* Sigma   = (const float*)d_in[6];
    const float* eps     = (const float*)d_in[7];
    float* out = (float*)d_out;
    float* ws  = (float*)d_ws;
    float* u   = ws + WS_U;

    const size_t need_bytes = ((size_t)WS_U + (size_t)TTg * BB * LLg * KKg) * sizeof(float);
    const bool use_table = ws_size >= need_bytes;   // constant per harness -> graph-safe

    prep_kernel<<<1, 256, 0, stream>>>(beta, raw_rho, Sigma, ws);

    const int nthreads = (NROWS / 2) * KKg;         // 4M
    const int nblocks  = nthreads / 256;            // 15625, exact

    if (use_table) {
        u_kernel<<<(BB * LLg * KKg + 255) / 256, 256, 0, stream>>>(eps, ws, u);
        main_kernel<true><<<nblocks, 256, 0, stream>>>(X, bat, lea, sea, ws, u, eps, out);
    } else {
        main_kernel<false><<<nblocks, 256, 0, stream>>>(X, bat, lea, sea, ws, u, eps, out);
    }
}

// Round 3
// 400.618 us; speedup vs baseline: 1.2388x; 1.2388x over previous
//
#include <hip/hip_runtime.h>
#include <math.h>

// Problem constants (from reference):
#define NROWS 1000000
#define NF    64      // N_FIXED
#define BB    5000    // B
#define LLg   10      // L
#define TTg   25      // T
#define KKg   8       // K

// ws layout (in floats):
//   [0,   80)   rho = tanh(raw_rho)          (L,K)
//   [80, 160)   d   = diag(chol(Sigma[k]))   (L,K)
//   [1024, 1024+T*B*L*K)  u table (T,B,L,K)  40 MB
#define WS_RHO   0
#define WS_D     80
#define WS_U     1024

// ---------------------------------------------------------------------------
// Prep: rho = tanh(raw_rho); d = diag of per-k Cholesky(Sigma).
// ---------------------------------------------------------------------------
__global__ void prep_kernel(const float* __restrict__ raw_rho,
                            const float* __restrict__ Sigma,
                            float* __restrict__ ws) {
    const int tid = threadIdx.x;
    for (int i = tid; i < LLg * KKg; i += blockDim.x)
        ws[WS_RHO + i] = tanhf(raw_rho[i]);
    if (tid < KKg) {
        const int k = tid;
        float Lf[LLg][LLg];
        const float* S = Sigma + k * LLg * LLg;
        for (int i = 0; i < LLg; ++i) {
            for (int j = 0; j <= i; ++j) {
                float s = S[i * LLg + j];
                for (int m = 0; m < j; ++m) s -= Lf[i][m] * Lf[j][m];
                if (i == j) Lf[i][i] = sqrtf(s);
                else        Lf[i][j] = s / Lf[j][j];
            }
        }
        for (int l = 0; l < LLg; ++l)
            ws[WS_D + l * KKg + k] = Lf[l][l];
    }
}

// ---------------------------------------------------------------------------
// u table: AR(1) recurrence, one thread per (b,l,k). Stores coalesced per t.
// ---------------------------------------------------------------------------
__global__ __launch_bounds__(256) void u_kernel(const float* __restrict__ eps,
                                                const float* __restrict__ ws,
                                                float* __restrict__ u) {
    const int tid = blockIdx.x * blockDim.x + threadIdx.x;
    if (tid >= BB * LLg * KKg) return;
    const int k = tid % KKg;
    const int l = (tid / KKg) % LLg;
    const int b = tid / (KKg * LLg);
    const float rho = ws[WS_RHO + l * KKg + k];
    const float dv  = ws[WS_D   + l * KKg + k];
    const float* ep = eps + ((size_t)(b * LLg + l) * TTg) * KKg + k;
    float* up = u + (size_t)(b * LLg + l) * KKg + k;   // t=0 slot
    const size_t ustride = (size_t)BB * LLg * KKg;     // stride in t
    float uv = ep[0];
    up[0] = uv;
    for (int t = 1; t < TTg; ++t) {
        uv = rho * uv + dv * ep[(size_t)t * KKg];
        up[(size_t)t * ustride] = uv;
    }
}

// ---------------------------------------------------------------------------
// Main: out[row,k] = dot(X[row,:], beta[:,k]) + u[sea,bat,lea,k]
//
// f-split decomposition (R2's k-split was vmem-issue-bound: every lane read
// the whole X row -> 8x L1 delivery amplification, ~58 vmem instr / 2 rows).
// Here lane j of an 8-lane group reads ONLY X[row, j*8 .. j*8+8) (perfectly
// coalesced across the wave), holds beta[j*8..j*8+8)][0..8) in 64 VGPRs
// (one-shot from bank-conflict-padded LDS), accumulates partials for all 8 k,
// then a 3-stage __shfl_xor reduce-scatter (masks 4,2,1) leaves the full sum
// for k=j on lane j -- matching the coalesced u-gather and out store.
// Each group does 2 adjacent rows: 11 vmem wave-instr per 16 rows.
// ---------------------------------------------------------------------------
template <bool USE_TABLE>
__global__ __launch_bounds__(256) void main_kernel(
    const float* __restrict__ X,
    const int*   __restrict__ bat,
    const int*   __restrict__ lea,
    const int*   __restrict__ sea,
    const float* __restrict__ beta,
    const float* __restrict__ ws,
    const float* __restrict__ u_table,
    const float* __restrict__ eps,
    float*       __restrict__ out)
{
    // LDS beta, padded: slice j (f = j*8+ff) at stride 68 floats so the 8
    // lanes of a group hit disjoint bank quads (68%32=4 -> banks j*4..j*4+3).
    __shared__ float sbeta[8 * 68];
    for (int i = threadIdx.x; i < NF * KKg; i += blockDim.x) {
        const int f = i >> 3, k = i & 7;
        sbeta[(f >> 3) * 68 + (f & 7) * 8 + k] = beta[i];
    }
    __syncthreads();

    const int gt   = blockIdx.x * blockDim.x + threadIdx.x;
    const int j    = gt & 7;          // lane-in-group: f-slice owner AND final k owner
    const int g    = gt >> 3;         // group id, 0..499999
    const int row0 = g * 2;

    // --- ids for both rows (group-uniform int2 loads) ---
    const int2 bb = *(const int2*)(bat + row0);
    const int2 ll = *(const int2*)(lea + row0);
    const int2 tt = *(const int2*)(sea + row0);

    // --- X slices (coalesced: group reads contiguous 256 B per row) ---
    const float* xr0p = X + (size_t)row0 * NF + j * 8;
    const float* xr1p = X + (size_t)(row0 + 1) * NF + j * 8;
    float xr0[8], xr1[8];
    *(float4*)&xr0[0] = ((const float4*)xr0p)[0];
    *(float4*)&xr0[4] = ((const float4*)xr0p)[1];
    *(float4*)&xr1[0] = ((const float4*)xr1p)[0];
    *(float4*)&xr1[4] = ((const float4*)xr1p)[1];

    // --- u values for k=j (coalesced 32 B per group) ---
    float uv0, uv1;
    if (USE_TABLE) {
        uv0 = u_table[(((size_t)tt.x * BB + bb.x) * LLg + ll.x) * KKg + j];
        uv1 = u_table[(((size_t)tt.y * BB + bb.y) * LLg + ll.y) * KKg + j];
    } else {
        const float rho0 = ws[WS_RHO + ll.x * KKg + j];
        const float dv0  = ws[WS_D   + ll.x * KKg + j];
        const float* e0  = eps + ((size_t)(bb.x * LLg + ll.x) * TTg) * KKg + j;
        uv0 = e0[0];
        for (int s = 1; s <= tt.x; ++s) uv0 = rho0 * uv0 + dv0 * e0[(size_t)s * KKg];
        const float rho1 = ws[WS_RHO + ll.y * KKg + j];
        const float dv1  = ws[WS_D   + ll.y * KKg + j];
        const float* e1  = eps + ((size_t)(bb.y * LLg + ll.y) * TTg) * KKg + j;
        uv1 = e1[0];
        for (int s = 1; s <= tt.y; ++s) uv1 = rho1 * uv1 + dv1 * e1[(size_t)s * KKg];
    }

    // --- beta slice -> 64 VGPRs (one-shot, conflict-free ds_read_b128) ---
    float bv[8][8];   // [ff][k]
#pragma unroll
    for (int ff = 0; ff < 8; ++ff) {
        const float4* p = (const float4*)&sbeta[j * 68 + ff * 8];
        const float4 u0 = p[0], u1 = p[1];
        bv[ff][0] = u0.x; bv[ff][1] = u0.y; bv[ff][2] = u0.z; bv[ff][3] = u0.w;
        bv[ff][4] = u1.x; bv[ff][5] = u1.y; bv[ff][6] = u1.z; bv[ff][7] = u1.w;
    }

    // --- partial dot products: 8 f x 8 k per lane, both rows ---
    float p0[8], p1[8];
#pragma unroll
    for (int k = 0; k < 8; ++k) { p0[k] = 0.f; p1[k] = 0.f; }
#pragma unroll
    for (int ff = 0; ff < 8; ++ff) {
#pragma unroll
        for (int k = 0; k < 8; ++k) {
            p0[k] += xr0[ff] * bv[ff][k];
            p1[k] += xr1[ff] * bv[ff][k];
        }
    }

    // --- reduce-scatter across the 8-lane group: after stages 4,2,1 lane j
    //     holds the full sum for k=j (k bits chosen to match j's bits) ---
#pragma unroll
    for (int i = 0; i < 4; ++i) {
        const float s0 = (j & 4) ? p0[i] : p0[i + 4];
        const float s1 = (j & 4) ? p1[i] : p1[i + 4];
        const float k0 = (j & 4) ? p0[i + 4] : p0[i];
        const float k1 = (j & 4) ? p1[i + 4] : p1[i];
        p0[i] = k0 + __shfl_xor(s0, 4);
        p1[i] = k1 + __shfl_xor(s1, 4);
    }
#pragma unroll
    for (int i = 0; i < 2; ++i) {
        const float s0 = (j & 2) ? p0[i] : p0[i + 2];
        const float s1 = (j & 2) ? p1[i] : p1[i + 2];
        const float k0 = (j & 2) ? p0[i + 2] : p0[i];
        const float k1 = (j & 2) ? p1[i + 2] : p1[i];
        p0[i] = k0 + __shfl_xor(s0, 2);
        p1[i] = k1 + __shfl_xor(s1, 2);
    }
    {
        const float s0 = (j & 1) ? p0[0] : p0[1];
        const float s1 = (j & 1) ? p1[0] : p1[1];
        const float k0 = (j & 1) ? p0[1] : p0[0];
        const float k1 = (j & 1) ? p1[1] : p1[0];
        p0[0] = k0 + __shfl_xor(s0, 1);
        p1[0] = k1 + __shfl_xor(s1, 1);
    }

    // --- store (32 B contiguous per group) ---
    out[(size_t)row0 * KKg + j]       = p0[0] + uv0;
    out[(size_t)(row0 + 1) * KKg + j] = p1[0] + uv1;
}

extern "C" void kernel_launch(void* const* d_in, const int* in_sizes, int n_in,
                              void* d_out, int out_size, void* d_ws, size_t ws_size,
                              hipStream_t stream) {
    const float* X       = (const float*)d_in[0];
    const int*   bat     = (const int*)  d_in[1];
    const int*   lea     = (const int*)  d_in[2];
    const int*   sea     = (const int*)  d_in[3];
    const float* beta    = (const float*)d_in[4];
    const float* raw_rho = (const float*)d_in[5];
    const float* Sigma   = (const float*)d_in[6];
    const float* eps     = (const float*)d_in[7];
    float* out = (float*)d_out;
    float* ws  = (float*)d_ws;
    float* u   = ws + WS_U;

    const size_t need_bytes = ((size_t)WS_U + (size_t)TTg * BB * LLg * KKg) * sizeof(float);
    const bool use_table = ws_size >= need_bytes;   // constant per harness -> graph-safe

    prep_kernel<<<1, 128, 0, stream>>>(raw_rho, Sigma, ws);

    const int nthreads = (NROWS / 2) * KKg;         // 4M
    const int nblocks  = nthreads / 256;            // 15625, exact cover

    if (use_table) {
        u_kernel<<<(BB * LLg * KKg + 255) / 256, 256, 0, stream>>>(eps, ws, u);
        main_kernel<true><<<nblocks, 256, 0, stream>>>(X, bat, lea, sea, beta, ws, u, eps, out);
    } else {
        main_kernel<false><<<nblocks, 256, 0, stream>>>(X, bat, lea, sea, beta, ws, u, eps, out);
    }
}